// Round 2
// 2210.237 us; speedup vs baseline: 1.1865x; 1.1865x over previous
//
#include <hip/hip_runtime.h>
#include <hip/hip_bf16.h>
#include <cstdint>
#include <cstddef>

// Problem constants
#define DIMN   2048
#define BATCH  16384
#define HID    5324
#define HP     5376   // HID padded to multiple of 256

typedef __bf16 bf16;
typedef __attribute__((ext_vector_type(8))) __bf16 bf16x8;
typedef __attribute__((ext_vector_type(4))) float floatx4;

#define GAS __attribute__((address_space(1)))
#define LAS __attribute__((address_space(3)))

// async global->LDS, 16B per lane. LDS dest is wave-uniform base + lane*16.
__device__ __forceinline__ void async_copy16(const bf16* g, bf16* l) {
    __builtin_amdgcn_global_load_lds((const GAS uint32_t*)g, (LAS uint32_t*)l, 16, 0, 0);
}

// ---------------------------------------------------------------------------
// GEMM: C[M][N] = A[M][K] @ W[N][K]^T   (bf16 inputs, fp32 accumulate)
//
// BM=256 BN=256 BK=32; 512 threads = 8 waves (2M x 4N); per-wave 128x64 out.
// 3-stage STATIC LDS pipeline (96 KiB): stage tile t+2 while computing tile t,
// counted s_waitcnt vmcnt(4) once per K-tile (never drains in main loop),
// raw s_barrier (no __syncthreads drain), s_setprio(1) around MFMA clusters.
// NOTE: static __shared__ (96 KiB < 160 KiB gfx950 limit) — no dynamic-LDS
// launch arg, no hipFuncSetAttribute (which breaks graph capture).
//
// LDS XOR swizzle (granule16B ^= (row>>1)&3): applied as linear gload_lds dest
// + inverse-swizzled per-lane GLOBAL source + swizzled ds_read address
// (both-sides-or-neither, guide rule #21). Spreads each quad's 16 b128 reads
// across all 32 banks (2-way = free) instead of 4-way on 8 banks.
//
// MODE 0: bf16io[idx] = bf16(val + bias[col])                      (v proj)
// MODE 1: f32io[idx] += val + bias[col]                            (h2 = h + attn)
// MODE 2: bf16io[idx] = bf16(silu(val))                            (sa)
// MODE 3: bf16io[idx] = bf16(float(bf16io[idx]) * val)             (mid, in-place)
// MODE 4: f32io[idx] += val                                        (out = h2 + ffn)
// ---------------------------------------------------------------------------
template<int MODE>
__global__ __launch_bounds__(512, 2) void gemm_bt(
    const bf16* __restrict__ A, const bf16* __restrict__ W,
    const int K, const int N,
    const float* __restrict__ bias,
    float* __restrict__ f32io,
    bf16* __restrict__ bf16io)
{
    // 3 stages x (A 256x32 + B 256x32) bf16 = 3 * 16384 elems = 96 KiB static
    __shared__ __align__(16) bf16 lds[49152];

    const int tid  = threadIdx.x;
    const int lane = tid & 63;
    const int wv   = tid >> 6;      // 0..7
    const int wm   = wv >> 2;       // 0..1  (M half: 128 rows)
    const int wn   = wv & 3;        // 0..3  (N quarter: 64 cols)

    // XCD-aware bijective block swizzle (all our grids are multiples of 8)
    const int gx  = gridDim.x;
    const int nwg = gx * gridDim.y;
    int lin = blockIdx.y * gx + blockIdx.x;
    if ((nwg & 7) == 0) lin = (lin & 7) * (nwg >> 3) + (lin >> 3);
    const int bx = lin % gx, by = lin / gx;
    const int blockRow = by << 8;   // 256
    const int blockCol = bx << 8;   // 256

    // ---- staging: per K-tile, A = 2 insts, B = 2 insts, 16B/lane ----
    // inst i covers LDS rows [i*128 + wv*16, +16); lane>>2 = row-in-group,
    // lane&3 = 16B granule. Global source granule is INVERSE-swizzled so data
    // lands at the swizzled LDS position while the dest stays linear.
    const int sg = ((lane & 3) ^ ((lane >> 3) & 3)) * 8;   // source granule (elems)
    const bf16* pA[2];
    const bf16* pB[2];
#pragma unroll
    for (int i = 0; i < 2; i++) {
        pA[i] = A + (size_t)(blockRow + i * 128 + wv * 16 + (lane >> 2)) * K + sg;
        pB[i] = W + (size_t)(blockCol + i * 128 + wv * 16 + (lane >> 2)) * K + sg;
    }

    // ---- fragment read offsets (elements), swizzled granule ----
    const int m16 = lane & 15, quad = lane >> 4;
    const int rg = (quad ^ ((m16 >> 1) & 3)) * 8;          // read granule (elems)
    const int aBase = (wm * 128 + m16) * 32 + rg;          // + mi*512 (+2048 for mi>=4)
    const int bBase = 8192 + (wn * 64 + m16) * 32 + rg;    // + ni*512

    floatx4 acc[8][4];
    const floatx4 zero = {0.f, 0.f, 0.f, 0.f};
#pragma unroll
    for (int i = 0; i < 8; i++)
#pragma unroll
        for (int j = 0; j < 4; j++) acc[i][j] = zero;

    const int nt = K >> 5;   // K-tiles of 32 (always >= 64 here)

    // ---- prologue: tile0 -> stage0, tile1 -> stage1 ----
#pragma unroll
    for (int i = 0; i < 2; i++) {
        async_copy16(pA[i], &lds[i * 4096 + wv * 512]);
        async_copy16(pB[i], &lds[8192 + i * 4096 + wv * 512]);
    }
#pragma unroll
    for (int i = 0; i < 2; i++) { pA[i] += 32; pB[i] += 32; }
#pragma unroll
    for (int i = 0; i < 2; i++) {
        async_copy16(pA[i], &lds[16384 + i * 4096 + wv * 512]);
        async_copy16(pB[i], &lds[16384 + 8192 + i * 4096 + wv * 512]);
    }
#pragma unroll
    for (int i = 0; i < 2; i++) { pA[i] += 32; pB[i] += 32; }
    asm volatile("s_waitcnt vmcnt(4)" ::: "memory");   // tile0 landed, tile1 in flight
    __builtin_amdgcn_s_barrier();

    int sCur = 0, sNxt = 32768;
    for (int t = 0; t < nt; ++t) {
        const bool pf = (t + 2) < nt;

        // ---- phase 0: prefetch A-half of tile t+2; compute mi 0..3 ----
        if (pf) {
            async_copy16(pA[0], &lds[sNxt + wv * 512]);
            async_copy16(pA[1], &lds[sNxt + 4096 + wv * 512]);
        }
        bf16x8 bfr[4], afr[4];
#pragma unroll
        for (int j = 0; j < 4; j++) bfr[j] = *(const bf16x8*)&lds[sCur + bBase + j * 512];
#pragma unroll
        for (int i = 0; i < 4; i++) afr[i] = *(const bf16x8*)&lds[sCur + aBase + i * 512];
        __builtin_amdgcn_s_setprio(1);
#pragma unroll
        for (int i = 0; i < 4; i++)
#pragma unroll
            for (int j = 0; j < 4; j++)
                acc[i][j] = __builtin_amdgcn_mfma_f32_16x16x32_bf16(afr[i], bfr[j], acc[i][j], 0, 0, 0);
        __builtin_amdgcn_s_setprio(0);
        __builtin_amdgcn_s_barrier();

        // ---- phase 1: prefetch B-half of tile t+2; compute mi 4..7 ----
        if (pf) {
            async_copy16(pB[0], &lds[sNxt + 8192 + wv * 512]);
            async_copy16(pB[1], &lds[sNxt + 8192 + 4096 + wv * 512]);
            pA[0] += 32; pA[1] += 32; pB[0] += 32; pB[1] += 32;
        }
#pragma unroll
        for (int i = 0; i < 4; i++) afr[i] = *(const bf16x8*)&lds[sCur + aBase + 2048 + i * 512];
        __builtin_amdgcn_s_setprio(1);
#pragma unroll
        for (int i = 0; i < 4; i++)
#pragma unroll
            for (int j = 0; j < 4; j++)
                acc[i + 4][j] = __builtin_amdgcn_mfma_f32_16x16x32_bf16(afr[i], bfr[j], acc[i + 4][j], 0, 0, 0);
        __builtin_amdgcn_s_setprio(0);

        // tile t+1 must be fully landed; tile t+2's 4 loads stay in flight
        if (pf) { asm volatile("s_waitcnt vmcnt(4)" ::: "memory"); }
        else    { asm volatile("s_waitcnt vmcnt(0)" ::: "memory"); }
        __builtin_amdgcn_s_barrier();

        sCur = (sCur == 32768) ? 0 : sCur + 16384;
        sNxt = (sNxt == 32768) ? 0 : sNxt + 16384;
    }

    // ---- epilogue: C/D layout col=lane&15, row=quad*4+reg  [verified m89/m91] ----
#pragma unroll
    for (int j = 0; j < 4; j++) {
        const int col = blockCol + wn * 64 + j * 16 + m16;
        float bv = 0.f;
        if (MODE == 0 || MODE == 1) bv = bias[col];
#pragma unroll
        for (int i = 0; i < 8; i++) {
            const int row0 = blockRow + wm * 128 + i * 16 + quad * 4;
#pragma unroll
            for (int r = 0; r < 4; r++) {
                const size_t idx = (size_t)(row0 + r) * N + col;
                const float val = acc[i][j][r];
                if (MODE == 0) {
                    bf16io[idx] = (bf16)(val + bv);
                } else if (MODE == 1) {
                    f32io[idx] = f32io[idx] + val + bv;
                } else if (MODE == 2) {
                    bf16io[idx] = (bf16)(val / (1.f + __expf(-val)));
                } else if (MODE == 3) {
                    const float m = (float)bf16io[idx] * val;
                    bf16io[idx] = (bf16)m;
                } else {
                    f32io[idx] = f32io[idx] + val;
                }
            }
        }
    }
}

// ---------------------------------------------------------------------------
// h = x + state (fp32, to d_out); hn = bf16(h / max(||h||,eps) / sqrt(DIM) * g)
// one block (256 thr) per row of 2048
// ---------------------------------------------------------------------------
__global__ __launch_bounds__(256) void rms_add_kernel(
    const float* __restrict__ x, const float* __restrict__ st,
    const float* __restrict__ g, float* __restrict__ h, bf16* __restrict__ hn)
{
    const int row = blockIdx.x;
    const int tid = threadIdx.x;
    const float4* x4 = (const float4*)(x + (size_t)row * DIMN);
    const float4* s4 = (const float4*)(st + (size_t)row * DIMN);
    float4* h4 = (float4*)(h + (size_t)row * DIMN);
    const float4* g4 = (const float4*)g;

    float4 hv[2];
    float ss = 0.f;
#pragma unroll
    for (int c = 0; c < 2; c++) {
        const int i = tid + c * 256;
        const float4 a = x4[i];
        const float4 b = s4[i];
        float4 t;
        t.x = a.x + b.x; t.y = a.y + b.y; t.z = a.z + b.z; t.w = a.w + b.w;
        h4[i] = t;
        hv[c] = t;
        ss += t.x * t.x + t.y * t.y + t.z * t.z + t.w * t.w;
    }
#pragma unroll
    for (int off = 32; off; off >>= 1) ss += __shfl_xor(ss, off, 64);
    __shared__ float red[4];
    if ((tid & 63) == 0) red[tid >> 6] = ss;
    __syncthreads();
    const float tot = red[0] + red[1] + red[2] + red[3];
    const float scale = 0.02209708691207961f / fmaxf(sqrtf(tot), 1e-12f);

    bf16* o = hn + (size_t)row * DIMN;
#pragma unroll
    for (int c = 0; c < 2; c++) {
        const int i = tid + c * 256;
        const float4 gv = g4[i];
        const float4 t = hv[c];
        o[i * 4 + 0] = (bf16)(t.x * scale * gv.x);
        o[i * 4 + 1] = (bf16)(t.y * scale * gv.y);
        o[i * 4 + 2] = (bf16)(t.z * scale * gv.z);
        o[i * 4 + 3] = (bf16)(t.w * scale * gv.w);
    }
}

// rmsnorm only (reads h2, writes hn2)
__global__ __launch_bounds__(256) void rms_kernel(
    const float* __restrict__ h, const float* __restrict__ g, bf16* __restrict__ hn)
{
    const int row = blockIdx.x;
    const int tid = threadIdx.x;
    const float4* h4 = (const float4*)(h + (size_t)row * DIMN);
    const float4* g4 = (const float4*)g;

    float4 hv[2];
    float ss = 0.f;
#pragma unroll
    for (int c = 0; c < 2; c++) {
        const int i = tid + c * 256;
        const float4 t = h4[i];
        hv[c] = t;
        ss += t.x * t.x + t.y * t.y + t.z * t.z + t.w * t.w;
    }
#pragma unroll
    for (int off = 32; off; off >>= 1) ss += __shfl_xor(ss, off, 64);
    __shared__ float red[4];
    if ((tid & 63) == 0) red[tid >> 6] = ss;
    __syncthreads();
    const float tot = red[0] + red[1] + red[2] + red[3];
    const float scale = 0.02209708691207961f / fmaxf(sqrtf(tot), 1e-12f);

    bf16* o = hn + (size_t)row * DIMN;
#pragma unroll
    for (int c = 0; c < 2; c++) {
        const int i = tid + c * 256;
        const float4 gv = g4[i];
        const float4 t = hv[c];
        o[i * 4 + 0] = (bf16)(t.x * scale * gv.x);
        o[i * 4 + 1] = (bf16)(t.y * scale * gv.y);
        o[i * 4 + 2] = (bf16)(t.z * scale * gv.z);
        o[i * 4 + 3] = (bf16)(t.w * scale * gv.w);
    }
}

// fp32 -> bf16 weight conversion with zero-padding outside (srcRows, srcCols)
__global__ __launch_bounds__(256) void cvt_pad_kernel(
    const float* __restrict__ src, bf16* __restrict__ dst,
    const int srcRows, const int srcCols, const int dstCols)
{
    const int col = blockIdx.x * 256 + threadIdx.x;
    const int row = blockIdx.y;
    if (col >= dstCols) return;
    float v = 0.f;
    if (row < srcRows && col < srcCols) v = src[(size_t)row * srcCols + col];
    dst[(size_t)row * dstCols + col] = (bf16)v;
}

// ---------------------------------------------------------------------------
extern "C" void kernel_launch(void* const* d_in, const int* in_sizes, int n_in,
                              void* d_out, int out_size, void* d_ws, size_t ws_size,
                              hipStream_t stream)
{
    const float* x   = (const float*)d_in[0];
    const float* st  = (const float*)d_in[1];
    const float* g1  = (const float*)d_in[2];
    const float* g2  = (const float*)d_in[3];
    const float* ipw = (const float*)d_in[4];
    const float* ipb = (const float*)d_in[5];
    const float* opw = (const float*)d_in[6];
    const float* opb = (const float*)d_in[7];
    const float* w1  = (const float*)d_in[8];
    const float* w2  = (const float*)d_in[9];
    const float* w3  = (const float*)d_in[10];
    float* out = (float*)d_out;   // holds h, then h2 (in-place), then final out (in-place)

    // workspace layout (bytes)
    char* wsb = (char*)d_ws;
    bf16* hn  = (bf16*)(wsb + 0);           // 16384*2048 bf16 = 64 MiB (hn, then hn2)
    bf16* vb  = (bf16*)(wsb + 67108864);    // 64 MiB (v)
    bf16* sa  = (bf16*)(wsb + 134217728);   // 16384*5376 bf16 = 168 MiB (silu(a), then mid)
    bf16* wvb = (bf16*)(wsb + 310378496);   // 2048*2048 bf16 = 8 MiB
    bf16* wob = (bf16*)(wsb + 318767104);   // 8 MiB
    bf16* w1b = (bf16*)(wsb + 327155712);   // 5376*2048 = 21 MiB
    bf16* w2b = (bf16*)(wsb + 349175808);   // 21 MiB
    bf16* w3b = (bf16*)(wsb + 371195904);   // 2048*5376 = 21 MiB  (end: 393216000)

    // weight conversions (bf16, zero-padded to HP where needed)
    cvt_pad_kernel<<<dim3(8, 2048), 256, 0, stream>>>(ipw + (size_t)2 * DIMN * DIMN, wvb, 2048, 2048, 2048);
    cvt_pad_kernel<<<dim3(8, 2048), 256, 0, stream>>>(opw, wob, 2048, 2048, 2048);
    cvt_pad_kernel<<<dim3(8, HP),   256, 0, stream>>>(w1, w1b, HID, 2048, 2048);   // rows >= HID -> 0
    cvt_pad_kernel<<<dim3(8, HP),   256, 0, stream>>>(w2, w2b, HID, 2048, 2048);
    cvt_pad_kernel<<<dim3(21, 2048),256, 0, stream>>>(w3, w3b, 2048, HID, HP);     // cols >= HID -> 0

    // h = x + state (fp32 in d_out); hn = rmsnorm(h, g1) bf16
    rms_add_kernel<<<BATCH, 256, 0, stream>>>(x, st, g1, out, hn);

    // v = hn @ wv^T + bv   (bf16 out)
    gemm_bt<0><<<dim3(8, 64), 512, 0, stream>>>(hn, wvb, 2048, 2048, ipb + 2 * DIMN, nullptr, vb);

    // h2 = h + v @ wo^T + bo   (fp32, in-place in d_out)
    gemm_bt<1><<<dim3(8, 64), 512, 0, stream>>>(vb, wob, 2048, 2048, opb, out, nullptr);

    // hn2 = rmsnorm(h2, g2) bf16 (reuse hn buffer)
    rms_kernel<<<BATCH, 256, 0, stream>>>(out, g2, hn);

    // sa = silu(hn2 @ w1p^T)   (bf16)
    gemm_bt<2><<<dim3(21, 64), 512, 0, stream>>>(hn, w1b, 2048, HP, nullptr, nullptr, sa);

    // mid = sa * (hn2 @ w2p^T)   (bf16, in-place in sa)
    gemm_bt<3><<<dim3(21, 64), 512, 0, stream>>>(hn, w2b, 2048, HP, nullptr, nullptr, sa);

    // out = h2 + mid @ w3p^T   (fp32, in-place in d_out)
    gemm_bt<4><<<dim3(8, 64), 512, 0, stream>>>(sa, w3b, HP, 2048, nullptr, out, nullptr);
}

// Round 3
// 2189.079 us; speedup vs baseline: 1.1979x; 1.0097x over previous
//
#include <hip/hip_runtime.h>
#include <hip/hip_bf16.h>
#include <cstdint>
#include <cstddef>

// Problem constants
#define DIMN   2048
#define BATCH  16384
#define HID    5324
#define HP     5376   // HID padded to multiple of 256

typedef __bf16 bf16;
typedef __attribute__((ext_vector_type(8))) __bf16 bf16x8;
typedef __attribute__((ext_vector_type(4))) float floatx4;

#define GAS __attribute__((address_space(1)))
#define LAS __attribute__((address_space(3)))

// async global->LDS, 16B per lane. LDS dest is wave-uniform base + lane*16.
__device__ __forceinline__ void async_copy16(const bf16* g, bf16* l) {
    __builtin_amdgcn_global_load_lds((const GAS uint32_t*)g, (LAS uint32_t*)l, 16, 0, 0);
}

// ---------------------------------------------------------------------------
// GEMM: C[M][N] = A[M][K] @ W[N][K]^T   (bf16 inputs, fp32 accumulate)
//
// BM=BN=256, BK=32; 512 threads = 8 waves (2M x 4N); per-wave 128x64 out.
// 3-stage STATIC LDS pipeline (96 KiB): stage tile t+2 while computing tile t.
// Each K-tile = 4 quadrant phases of 8 MFMA:
//   {ds_reads for quadrant; 1 gload_lds; sched_barrier(0); s_barrier;
//    setprio(1); 8 MFMA; setprio(0)}
// Only ONE trailing barrier per tile (after counted vmcnt(4)).  A wave leaving
// its MFMA cluster immediately issues the next phase's ds_reads while slower
// waves still MFMA -> LDS pipe and MFMA pipe overlap across waves.  This is
// safe ONLY because staging targets the dead 3rd buffer (no liveness hazard).
// vmcnt ledger (per wave): 4 staged insts/iter; vmcnt(4) at iter end forces
// all older (tile t+1) loads landed; tail uses vmcnt(0).  Same guarantees as
// the harness-verified round-2 kernel.
//
// LDS XOR swizzle (granule16B ^= (row>>1)&3): linear gload_lds dest +
// inverse-swizzled GLOBAL source + swizzled ds_read address (rule #21).
// Verified round 2: SQ_LDS_BANK_CONFLICT == 0.
//
// MODE 0: bf16io[idx] = bf16(val + bias[col])                      (v proj)
// MODE 1: f32io[idx] += val + bias[col]                            (h2 = h + attn)
// MODE 2: bf16io[idx] = bf16(silu(val))                            (sa)
// MODE 3: bf16io[idx] = bf16(float(bf16io[idx]) * val)             (mid, in-place)
// MODE 4: f32io[idx] += val                                        (out = h2 + ffn)
// ---------------------------------------------------------------------------
template<int MODE>
__global__ __launch_bounds__(512, 2) void gemm_bt(
    const bf16* __restrict__ A, const bf16* __restrict__ W,
    const int K, const int N,
    const float* __restrict__ bias,
    float* __restrict__ f32io,
    bf16* __restrict__ bf16io)
{
    // 3 stages x (A 256x32 + B 256x32) bf16 = 3 * 16384 elems = 96 KiB static
    __shared__ __align__(16) bf16 lds[49152];

    const int tid  = threadIdx.x;
    const int lane = tid & 63;
    const int wv   = tid >> 6;      // 0..7
    const int wm   = wv >> 2;       // 0..1  (M half: 128 rows)
    const int wn   = wv & 3;        // 0..3  (N quarter: 64 cols)

    // XCD-aware bijective block swizzle (all our grids are multiples of 8)
    const int gx  = gridDim.x;
    const int nwg = gx * gridDim.y;
    int lin = blockIdx.y * gx + blockIdx.x;
    if ((nwg & 7) == 0) lin = (lin & 7) * (nwg >> 3) + (lin >> 3);
    const int bx = lin % gx, by = lin / gx;
    const int blockRow = by << 8;   // 256
    const int blockCol = bx << 8;   // 256

    // ---- staging: per K-tile, A = 2 insts, B = 2 insts, 16B per lane ----
    // inst i covers LDS rows [i*128 + wv*16, +16); lane>>2 = row-in-group,
    // lane&3 = 16B granule. Global source granule is INVERSE-swizzled so data
    // lands at the swizzled LDS position while the dest stays linear.
    const int sg = ((lane & 3) ^ ((lane >> 3) & 3)) * 8;   // source granule (elems)
    const bf16* pA[2];
    const bf16* pB[2];
#pragma unroll
    for (int i = 0; i < 2; i++) {
        pA[i] = A + (size_t)(blockRow + i * 128 + wv * 16 + (lane >> 2)) * K + sg;
        pB[i] = W + (size_t)(blockCol + i * 128 + wv * 16 + (lane >> 2)) * K + sg;
    }

    // ---- fragment read offsets (elements), swizzled granule ----
    const int m16 = lane & 15, quad = lane >> 4;
    const int rg = (quad ^ ((m16 >> 1) & 3)) * 8;          // read granule (elems)
    const int aBase = (wm * 128 + m16) * 32 + rg;          // + mi*512 (+2048 for mi>=4)
    const int bBase = 8192 + (wn * 64 + m16) * 32 + rg;    // + nj*512

    floatx4 acc[8][4];
    const floatx4 zero = {0.f, 0.f, 0.f, 0.f};
#pragma unroll
    for (int i = 0; i < 8; i++)
#pragma unroll
        for (int j = 0; j < 4; j++) acc[i][j] = zero;

    const int nt = K >> 5;   // K-tiles of 32 (always >= 64 here)

    // ---- prologue: tile0 -> stage0, tile1 -> stage1 ----
#pragma unroll
    for (int i = 0; i < 2; i++) {
        async_copy16(pA[i], &lds[i * 4096 + wv * 512]);
        async_copy16(pB[i], &lds[8192 + i * 4096 + wv * 512]);
    }
#pragma unroll
    for (int i = 0; i < 2; i++) { pA[i] += 32; pB[i] += 32; }
#pragma unroll
    for (int i = 0; i < 2; i++) {
        async_copy16(pA[i], &lds[16384 + i * 4096 + wv * 512]);
        async_copy16(pB[i], &lds[16384 + 8192 + i * 4096 + wv * 512]);
    }
#pragma unroll
    for (int i = 0; i < 2; i++) { pA[i] += 32; pB[i] += 32; }
    asm volatile("s_waitcnt vmcnt(4)" ::: "memory");   // tile0 landed, tile1 in flight
    __builtin_amdgcn_s_barrier();

    int sCur = 0, sNxt = 32768;
    for (int t = 0; t < nt; ++t) {
        const bool pf = (t + 2) < nt;
        bf16x8 a0[4], a1[4], b01[2], b23[2];

        // ---- phase 1: read a0 (mi0-3) + b01; stage A-half0(t+2); Q(mi0-3 x nj0-1)
#pragma unroll
        for (int i = 0; i < 4; i++) a0[i] = *(const bf16x8*)&lds[sCur + aBase + i * 512];
#pragma unroll
        for (int j = 0; j < 2; j++) b01[j] = *(const bf16x8*)&lds[sCur + bBase + j * 512];
        if (pf) async_copy16(pA[0], &lds[sNxt + wv * 512]);
        __builtin_amdgcn_sched_barrier(0);
        __builtin_amdgcn_s_barrier();
        __builtin_amdgcn_s_setprio(1);
#pragma unroll
        for (int i = 0; i < 4; i++)
#pragma unroll
            for (int j = 0; j < 2; j++)
                acc[i][j] = __builtin_amdgcn_mfma_f32_16x16x32_bf16(a0[i], b01[j], acc[i][j], 0, 0, 0);
        __builtin_amdgcn_s_setprio(0);

        // ---- phase 2: read a1 (mi4-7); stage A-half1(t+2); Q(mi4-7 x nj0-1)
#pragma unroll
        for (int i = 0; i < 4; i++) a1[i] = *(const bf16x8*)&lds[sCur + aBase + 2048 + i * 512];
        if (pf) async_copy16(pA[1], &lds[sNxt + 4096 + wv * 512]);
        __builtin_amdgcn_sched_barrier(0);
        __builtin_amdgcn_s_barrier();
        __builtin_amdgcn_s_setprio(1);
#pragma unroll
        for (int i = 0; i < 4; i++)
#pragma unroll
            for (int j = 0; j < 2; j++)
                acc[i + 4][j] = __builtin_amdgcn_mfma_f32_16x16x32_bf16(a1[i], b01[j], acc[i + 4][j], 0, 0, 0);
        __builtin_amdgcn_s_setprio(0);

        // ---- phase 3: read b23; stage B-half0(t+2); Q(mi4-7 x nj2-3)
#pragma unroll
        for (int j = 0; j < 2; j++) b23[j] = *(const bf16x8*)&lds[sCur + bBase + (2 + j) * 512];
        if (pf) async_copy16(pB[0], &lds[sNxt + 8192 + wv * 512]);
        __builtin_amdgcn_sched_barrier(0);
        __builtin_amdgcn_s_barrier();
        __builtin_amdgcn_s_setprio(1);
#pragma unroll
        for (int i = 0; i < 4; i++)
#pragma unroll
            for (int j = 0; j < 2; j++)
                acc[i + 4][j + 2] = __builtin_amdgcn_mfma_f32_16x16x32_bf16(a1[i], b23[j], acc[i + 4][j + 2], 0, 0, 0);
        __builtin_amdgcn_s_setprio(0);

        // ---- phase 4: no reads (a0 held); stage B-half1(t+2); Q(mi0-3 x nj2-3)
        if (pf) {
            async_copy16(pB[1], &lds[sNxt + 8192 + 4096 + wv * 512]);
            pA[0] += 32; pA[1] += 32; pB[0] += 32; pB[1] += 32;
        }
        __builtin_amdgcn_sched_barrier(0);
        __builtin_amdgcn_s_barrier();
        __builtin_amdgcn_s_setprio(1);
#pragma unroll
        for (int i = 0; i < 4; i++)
#pragma unroll
            for (int j = 0; j < 2; j++)
                acc[i][j + 2] = __builtin_amdgcn_mfma_f32_16x16x32_bf16(a0[i], b23[j], acc[i][j + 2], 0, 0, 0);
        __builtin_amdgcn_s_setprio(0);

        // tile t+1 must be fully landed; tile t+2's 4 loads stay in flight
        if (pf) { asm volatile("s_waitcnt vmcnt(4)" ::: "memory"); }
        else    { asm volatile("s_waitcnt vmcnt(0)" ::: "memory"); }
        __builtin_amdgcn_s_barrier();

        sCur = (sCur == 32768) ? 0 : sCur + 16384;
        sNxt = (sNxt == 32768) ? 0 : sNxt + 16384;
    }

    // ---- epilogue: C/D layout col=lane&15, row=quad*4+reg  [verified m89/m91] ----
#pragma unroll
    for (int j = 0; j < 4; j++) {
        const int col = blockCol + wn * 64 + j * 16 + m16;
        float bv = 0.f;
        if (MODE == 0 || MODE == 1) bv = bias[col];
#pragma unroll
        for (int i = 0; i < 8; i++) {
            const int row0 = blockRow + wm * 128 + i * 16 + quad * 4;
#pragma unroll
            for (int r = 0; r < 4; r++) {
                const size_t idx = (size_t)(row0 + r) * N + col;
                const float val = acc[i][j][r];
                if (MODE == 0) {
                    bf16io[idx] = (bf16)(val + bv);
                } else if (MODE == 1) {
                    f32io[idx] = f32io[idx] + val + bv;
                } else if (MODE == 2) {
                    bf16io[idx] = (bf16)(val / (1.f + __expf(-val)));
                } else if (MODE == 3) {
                    const float m = (float)bf16io[idx] * val;
                    bf16io[idx] = (bf16)m;
                } else {
                    f32io[idx] = f32io[idx] + val;
                }
            }
        }
    }
}

// ---------------------------------------------------------------------------
// h = x + state (fp32, to d_out); hn = bf16(h / max(||h||,eps) / sqrt(DIM) * g)
// one block (256 thr) per row of 2048
// ---------------------------------------------------------------------------
__global__ __launch_bounds__(256) void rms_add_kernel(
    const float* __restrict__ x, const float* __restrict__ st,
    const float* __restrict__ g, float* __restrict__ h, bf16* __restrict__ hn)
{
    const int row = blockIdx.x;
    const int tid = threadIdx.x;
    const float4* x4 = (const float4*)(x + (size_t)row * DIMN);
    const float4* s4 = (const float4*)(st + (size_t)row * DIMN);
    float4* h4 = (float4*)(h + (size_t)row * DIMN);
    const float4* g4 = (const float4*)g;

    float4 hv[2];
    float ss = 0.f;
#pragma unroll
    for (int c = 0; c < 2; c++) {
        const int i = tid + c * 256;
        const float4 a = x4[i];
        const float4 b = s4[i];
        float4 t;
        t.x = a.x + b.x; t.y = a.y + b.y; t.z = a.z + b.z; t.w = a.w + b.w;
        h4[i] = t;
        hv[c] = t;
        ss += t.x * t.x + t.y * t.y + t.z * t.z + t.w * t.w;
    }
#pragma unroll
    for (int off = 32; off; off >>= 1) ss += __shfl_xor(ss, off, 64);
    __shared__ float red[4];
    if ((tid & 63) == 0) red[tid >> 6] = ss;
    __syncthreads();
    const float tot = red[0] + red[1] + red[2] + red[3];
    const float scale = 0.02209708691207961f / fmaxf(sqrtf(tot), 1e-12f);

    bf16* o = hn + (size_t)row * DIMN;
#pragma unroll
    for (int c = 0; c < 2; c++) {
        const int i = tid + c * 256;
        const float4 gv = g4[i];
        const float4 t = hv[c];
        o[i * 4 + 0] = (bf16)(t.x * scale * gv.x);
        o[i * 4 + 1] = (bf16)(t.y * scale * gv.y);
        o[i * 4 + 2] = (bf16)(t.z * scale * gv.z);
        o[i * 4 + 3] = (bf16)(t.w * scale * gv.w);
    }
}

// rmsnorm only (reads h2, writes hn2)
__global__ __launch_bounds__(256) void rms_kernel(
    const float* __restrict__ h, const float* __restrict__ g, bf16* __restrict__ hn)
{
    const int row = blockIdx.x;
    const int tid = threadIdx.x;
    const float4* h4 = (const float4*)(h + (size_t)row * DIMN);
    const float4* g4 = (const float4*)g;

    float4 hv[2];
    float ss = 0.f;
#pragma unroll
    for (int c = 0; c < 2; c++) {
        const int i = tid + c * 256;
        const float4 t = h4[i];
        hv[c] = t;
        ss += t.x * t.x + t.y * t.y + t.z * t.z + t.w * t.w;
    }
#pragma unroll
    for (int off = 32; off; off >>= 1) ss += __shfl_xor(ss, off, 64);
    __shared__ float red[4];
    if ((tid & 63) == 0) red[tid >> 6] = ss;
    __syncthreads();
    const float tot = red[0] + red[1] + red[2] + red[3];
    const float scale = 0.02209708691207961f / fmaxf(sqrtf(tot), 1e-12f);

    bf16* o = hn + (size_t)row * DIMN;
#pragma unroll
    for (int c = 0; c < 2; c++) {
        const int i = tid + c * 256;
        const float4 gv = g4[i];
        const float4 t = hv[c];
        o[i * 4 + 0] = (bf16)(t.x * scale * gv.x);
        o[i * 4 + 1] = (bf16)(t.y * scale * gv.y);
        o[i * 4 + 2] = (bf16)(t.z * scale * gv.z);
        o[i * 4 + 3] = (bf16)(t.w * scale * gv.w);
    }
}

// fp32 -> bf16 weight conversion with zero-padding outside (srcRows, srcCols)
__global__ __launch_bounds__(256) void cvt_pad_kernel(
    const float* __restrict__ src, bf16* __restrict__ dst,
    const int srcRows, const int srcCols, const int dstCols)
{
    const int col = blockIdx.x * 256 + threadIdx.x;
    const int row = blockIdx.y;
    if (col >= dstCols) return;
    float v = 0.f;
    if (row < srcRows && col < srcCols) v = src[(size_t)row * srcCols + col];
    dst[(size_t)row * dstCols + col] = (bf16)v;
}

// ---------------------------------------------------------------------------
extern "C" void kernel_launch(void* const* d_in, const int* in_sizes, int n_in,
                              void* d_out, int out_size, void* d_ws, size_t ws_size,
                              hipStream_t stream)
{
    const float* x   = (const float*)d_in[0];
    const float* st  = (const float*)d_in[1];
    const float* g1  = (const float*)d_in[2];
    const float* g2  = (const float*)d_in[3];
    const float* ipw = (const float*)d_in[4];
    const float* ipb = (const float*)d_in[5];
    const float* opw = (const float*)d_in[6];
    const float* opb = (const float*)d_in[7];
    const float* w1  = (const float*)d_in[8];
    const float* w2  = (const float*)d_in[9];
    const float* w3  = (const float*)d_in[10];
    float* out = (float*)d_out;   // holds h, then h2 (in-place), then final out (in-place)

    // workspace layout (bytes)
    char* wsb = (char*)d_ws;
    bf16* hn  = (bf16*)(wsb + 0);           // 16384*2048 bf16 = 64 MiB (hn, then hn2)
    bf16* vb  = (bf16*)(wsb + 67108864);    // 64 MiB (v)
    bf16* sa  = (bf16*)(wsb + 134217728);   // 16384*5376 bf16 = 168 MiB (silu(a), then mid)
    bf16* wvb = (bf16*)(wsb + 310378496);   // 2048*2048 bf16 = 8 MiB
    bf16* wob = (bf16*)(wsb + 318767104);   // 8 MiB
    bf16* w1b = (bf16*)(wsb + 327155712);   // 5376*2048 = 21 MiB
    bf16* w2b = (bf16*)(wsb + 349175808);   // 21 MiB
    bf16* w3b = (bf16*)(wsb + 371195904);   // 2048*5376 = 21 MiB  (end: 393216000)

    // weight conversions (bf16, zero-padded to HP where needed)
    cvt_pad_kernel<<<dim3(8, 2048), 256, 0, stream>>>(ipw + (size_t)2 * DIMN * DIMN, wvb, 2048, 2048, 2048);
    cvt_pad_kernel<<<dim3(8, 2048), 256, 0, stream>>>(opw, wob, 2048, 2048, 2048);
    cvt_pad_kernel<<<dim3(8, HP),   256, 0, stream>>>(w1, w1b, HID, 2048, 2048);   // rows >= HID -> 0
    cvt_pad_kernel<<<dim3(8, HP),   256, 0, stream>>>(w2, w2b, HID, 2048, 2048);
    cvt_pad_kernel<<<dim3(21, 2048),256, 0, stream>>>(w3, w3b, 2048, HID, HP);     // cols >= HID -> 0

    // h = x + state (fp32 in d_out); hn = rmsnorm(h, g1) bf16
    rms_add_kernel<<<BATCH, 256, 0, stream>>>(x, st, g1, out, hn);

    // v = hn @ wv^T + bv   (bf16 out)
    gemm_bt<0><<<dim3(8, 64), 512, 0, stream>>>(hn, wvb, 2048, 2048, ipb + 2 * DIMN, nullptr, vb);

    // h2 = h + v @ wo^T + bo   (fp32, in-place in d_out)
    gemm_bt<1><<<dim3(8, 64), 512, 0, stream>>>(vb, wob, 2048, 2048, opb, out, nullptr);

    // hn2 = rmsnorm(h2, g2) bf16 (reuse hn buffer)
    rms_kernel<<<BATCH, 256, 0, stream>>>(out, g2, hn);

    // sa = silu(hn2 @ w1p^T)   (bf16)
    gemm_bt<2><<<dim3(21, 64), 512, 0, stream>>>(hn, w1b, 2048, HP, nullptr, nullptr, sa);

    // mid = sa * (hn2 @ w2p^T)   (bf16, in-place in sa)
    gemm_bt<3><<<dim3(21, 64), 512, 0, stream>>>(hn, w2b, 2048, HP, nullptr, nullptr, sa);

    // out = h2 + mid @ w3p^T   (fp32, in-place in d_out)
    gemm_bt<4><<<dim3(8, 64), 512, 0, stream>>>(sa, w3b, HP, 2048, nullptr, out, nullptr);
}